// Round 13
// baseline (495.807 us; speedup 1.0000x reference)
//
#include <hip/hip_runtime.h>
#include <hip/hip_bf16.h>

typedef __attribute__((ext_vector_type(8))) short short8;
typedef __attribute__((ext_vector_type(4))) float f32x4;

// pack 8 fp32 -> 8 bf16 (RNE) as one short8 (4 VGPRs)
__device__ __forceinline__ short8 pack8(const f32x4& a, const f32x4& b) {
    union { __hip_bfloat162 h[4]; short8 s; } u;
    u.h[0] = __float22bfloat162_rn(make_float2(a[0], a[1]));
    u.h[1] = __float22bfloat162_rn(make_float2(a[2], a[3]));
    u.h[2] = __float22bfloat162_rn(make_float2(b[0], b[1]));
    u.h[3] = __float22bfloat162_rn(make_float2(b[2], b[3]));
    return u.s;
}

// r2..r7-proven involution swizzle (fallback kernel only)
__device__ __forceinline__ int swz4(int g) { return g ^ (((g >> 4) & 3) << 1); }

// async global->LDS DMA, 16B per lane; LDS dest = wave-uniform base + lane*16
#define GLDS(GP, LP)                                                          \
    __builtin_amdgcn_global_load_lds(                                         \
        (__attribute__((address_space(1))) void*)(void*)(GP),                 \
        (__attribute__((address_space(3))) void*)(void*)(LP), 16, 0, 0)

// ============================================================================
// Kernel 1 (r8/r9-proven): fp32 -> bf16 conversion + MFMA-granule relayout.
// Granule (idx, ks) = 1KB: lane l holds row idx*16+(l&15), k ks*32+(l>>4)*8..+8.
// W1b: [km][f 0..31][ks 0..15]; Xb (at +134217728 shorts): [mf 0..63][ks].
// ============================================================================
__global__ __launch_bounds__(256)
void ens_cvt(const float* __restrict__ X, const float* __restrict__ W1,
             short* __restrict__ WS)
{
    const int t = threadIdx.x, lane = t & 63, wv = t >> 6;
    const int g = blockIdx.x * 4 + wv;
    const int row16 = lane & 15, koct = lane >> 4;
    const float* src;
    short* dst;
    if (blockIdx.x < 4096) {                       // W1: g = km*32 + f
        const int km = g >> 5, f = g & 31;
        src = W1 + (size_t)km * 262144 + (size_t)(f * 16 + row16) * 512 + koct * 8;
        dst = WS + (size_t)km * 262144 + (size_t)(f * 16) * 512 + lane * 8;
    } else {                                       // X: mf = g - 16384 (0..63)
        const int mf = g - 16384;
        src = X + (size_t)(mf * 16 + row16) * 512 + koct * 8;
        dst = WS + 134217728ull + (size_t)(mf * 16) * 512 + lane * 8;
    }
#pragma unroll
    for (int ks = 0; ks < 16; ++ks) {
        f32x4 a = *(const f32x4*)(src + ks * 32);
        f32x4 b = *(const f32x4*)(src + ks * 32 + 4);
        *(short8*)(dst + ks * 512) = pack8(a, b);
    }
}

// ============================================================================
// Kernel 2: A-DIRECT hybrid. B (W1b) stages via GLDS into a 2x32KB LDS dbuf
// (conflict-free linear granules); A (Xb, 1MB, L1/L2-hot) loads DIRECT
// global->VGPR — pre-permuted granules are coalesced 16B/lane fragments.
// LDS pipe/K-tile drops 192->64 b128 reads (+32KB GLDS writes), well under
// the 2048-cyc MFMA floor; A latency hidden by 2-set rotation + counted vmcnt.
// Per-wave vmcnt FIFO ledger (GLDS counts in vmcnt too):
//   prologue: [4G][8P] vm(8) -> exit [8P]
//   ph0: +8Q +2G  -> vm(10) retires avP; lgkm(0) for bvP; MFMA P-half0
//   ph1: +2G      -> MFMA P-half1
//   ph2: +8P'     -> vm(12) retires avQ; lgkm(0) for bvQ; MFMA Q-half0
//   ph3: MFMA Q-half1; vm(8) retires 4G; barrier -> exit [8P']
//   kt=7: no GLDS/no P' -> vm(8)/vm(0).
// Race audit: GLDS(kt+1)->buf^1 while ds_reads hit buf; reads of buf^1 ended
// before kt-1's ph3 barrier; GLDS drains (vm(8)) before kt's ph3 barrier, so
// kt+1's reads are safe. Epilogue lout (20KB @ buf0) is disjoint from kt=7's
// read buffer (buf1).
// ============================================================================
#define SB __builtin_amdgcn_sched_barrier(0)

#define LOADAV(DST, AOFF)                                                     \
    _Pragma("unroll") for (int mi = 0; mi < 8; ++mi)                          \
        DST[mi] = *(const short8*)(pa + mi * 8192 + (AOFF));

#define RDB(DST, KKV)                                                         \
    _Pragma("unroll") for (int pp = 0; pp < 4; ++pp)                          \
        DST[pp] = *(const short8*)(rb +                                       \
            (((wn * 4 + pp) * 2 + (KKV)) << 10) + l16);

#define MFMA16H(AV, A0, BV)                                                   \
    __builtin_amdgcn_s_setprio(1);                                            \
    _Pragma("unroll") for (int ii = 0; ii < 4; ++ii)                          \
        _Pragma("unroll") for (int pp = 0; pp < 4; ++pp)                      \
            acc[(A0) + ii][pp] = __builtin_amdgcn_mfma_f32_16x16x32_bf16(     \
                AV[(A0) + ii], BV[pp], acc[(A0) + ii][pp], 0, 0, 0);          \
    __builtin_amdgcn_s_setprio(0);

__global__ __launch_bounds__(512, 2)
void ens_gemm_dma(const short* __restrict__ Xb, const short* __restrict__ W1b,
                  const float* __restrict__ B1, const float* __restrict__ W2,
                  const float* __restrict__ B2, float* __restrict__ out)
{
    extern __shared__ char smem[];
    const int t    = threadIdx.x;
    const int lane = t & 63;
    const int l16  = lane << 4;
    const int wv   = t >> 6;
    const int wm   = wv >> 2;     // 0..1
    const int wn   = wv & 3;      // 0..3

    // XCD-aware decode: 8 blocks of the same km adjacent on one XCD.
    const int bb  = blockIdx.x;
    const int xcd = bb & 7;
    const int j   = bb >> 3;
    const int km  = xcd * 64 + (j >> 3);   // 0..511
    const int sub = j & 7;
    const int mt  = sub >> 1;              // 0..3 (256-row batch tile)
    const int nt  = sub & 1;               // 0..1 (256-col n half)

    // A fragments: direct loads from pre-permuted Xb granules.
    const short* pa = Xb + (size_t)(mt * 16 + wm * 8) * 8192 + lane * 8;
    // B staging: wave wv stages f = {wv*2, wv*2+1} x kk{0,1} (4 granules).
    const short* gsrc = W1b + (size_t)km * 262144 +
                        (size_t)(nt * 16 + wv * 2) * 8192 + lane * 8;

    f32x4 acc[8][4];
#pragma unroll
    for (int i = 0; i < 8; ++i)
#pragma unroll
        for (int p = 0; p < 4; ++p)
            acc[i][p] = (f32x4)0.0f;

    short8 avP[8], avQ[8];
    short8 bvP[4], bvQ[4];

    // ---- prologue: GLDS B(tile0) + issue avP(kk0,t0); drain GLDS; publish --
    {
        char* wdst = smem + wv * 4096;
        GLDS(gsrc, wdst);            GLDS(gsrc + 512, wdst + 1024);
        GLDS(gsrc + 8192, wdst + 2048); GLDS(gsrc + 8704, wdst + 3072);
        SB;
        LOADAV(avP, 0);
        SB;
        asm volatile("s_waitcnt vmcnt(8)" ::: "memory");
        SB;
        __builtin_amdgcn_s_barrier();
    }

#pragma unroll 1
    for (int kt = 0; kt < 8; ++kt) {
        const char* rb = smem + (kt & 1) * 32768;
        char* wdst     = smem + ((kt + 1) & 1) * 32768 + wv * 4096;
        const int koff = (kt + 1) << 10;     // next tile's B src (shorts)
        const bool stage = (kt < 7);

        // ph0: issue avQ (this tile kk1) + bvP ds + GLDS half; wait avP+bvP
        LOADAV(avQ, (kt << 10) + 512);
        SB;
        RDB(bvP, 0);
        SB;
        if (stage) { GLDS(gsrc + koff, wdst); GLDS(gsrc + koff + 512, wdst + 1024); }
        SB;
        if (stage) { asm volatile("s_waitcnt vmcnt(10)" ::: "memory"); }
        else       { asm volatile("s_waitcnt vmcnt(8)"  ::: "memory"); }
        asm volatile("s_waitcnt lgkmcnt(0)" ::: "memory");
        SB;
        MFMA16H(avP, 0, bvP);
        SB;

        // ph1: issue bvQ ds + GLDS rest; MFMA P-half1
        RDB(bvQ, 1);
        SB;
        if (stage) { GLDS(gsrc + koff + 8192, wdst + 2048);
                     GLDS(gsrc + koff + 8704, wdst + 3072); }
        SB;
        MFMA16H(avP, 4, bvP);
        SB;

        // ph2: issue avP' (next tile kk0); wait avQ+bvQ; MFMA Q-half0
        if (stage) { LOADAV(avP, (kt + 1) << 10); }
        SB;
        if (stage) { asm volatile("s_waitcnt vmcnt(12)" ::: "memory"); }
        else       { asm volatile("s_waitcnt vmcnt(0)"  ::: "memory"); }
        asm volatile("s_waitcnt lgkmcnt(0)" ::: "memory");
        SB;
        MFMA16H(avQ, 0, bvQ);
        SB;

        // ph3: MFMA Q-half1; drain GLDS; tile barrier
        MFMA16H(avQ, 4, bvQ);
        SB;
        if (stage) {
            asm volatile("s_waitcnt vmcnt(8)" ::: "memory");
            SB;
            __builtin_amdgcn_s_barrier();
        }
    }

    // ---- epilogue: relu + dot(W2); 2 shfl rounds + LDS[256][20] reduce ----
    const int nc = lane & 15;
    const int kq = lane >> 4;
    float b1v[4], w2v[4];
#pragma unroll
    for (int pp = 0; pp < 4; ++pp) {
        int n = nt * 256 + (wn * 4 + pp) * 16 + nc;
        b1v[pp] = B1[km * 512 + n];
        w2v[pp] = W2[km * 512 + n];
    }

    float* lout = (float*)smem;   // 20KB in buf0; kt=7 read buf1 -> disjoint
#pragma unroll
    for (int i = 0; i < 8; ++i) {
#pragma unroll
        for (int r = 0; r < 4; ++r) {
            float s = 0.f;
#pragma unroll
            for (int pp = 0; pp < 4; ++pp) {
                float h = acc[i][pp][r] + b1v[pp];
                h = h > 0.f ? h : 0.f;
                s += h * w2v[pp];
            }
            s += __shfl_xor(s, 1, 64);
            s += __shfl_xor(s, 2, 64);
            if ((nc & 3) == 0) {
                int row = wm * 128 + i * 16 + kq * 4 + r;
                lout[row * 20 + wn * 4 + (nc >> 2)] = s;
            }
        }
    }
    __syncthreads();
    {
        int row = t >> 1, half = t & 1;
        const f32x4* p = (const f32x4*)(lout + row * 20 + half * 8);
        f32x4 a = p[0], b = p[1];
        float s = a[0] + a[1] + a[2] + a[3] + b[0] + b[1] + b[2] + b[3];
        s += __shfl_xor(s, 1, 64);
        if (half == 0) {
            if (nt == 0) s += B2[km];
            int bo = mt * 256 + row;
            // out[b, e, o] with k = o*E + e -> flat b*512 + (km%8)*64 + (km/8)
            atomicAdd(out + (size_t)bo * 512 + (km & 7) * 64 + (km >> 3), s);
        }
    }
}

// ============================================================================
// Fallback (r6 verbatim, 428 µs): used when ws_size < 269,484,032 bytes.
// ============================================================================
#define FISSUE(S, BASE, KT1)                                                  \
  do {                                                                        \
    const float* q_ = (BASE) + (KT1) * 64;                                    \
    S[0] = *(const f32x4*)q_;          S[1] = *(const f32x4*)(q_ + 4);        \
    S[2] = *(const f32x4*)(q_ + 32);   S[3] = *(const f32x4*)(q_ + 36);       \
    const float* q2_ = q_ + 65536;                                            \
    S[4] = *(const f32x4*)q2_;         S[5] = *(const f32x4*)(q2_ + 4);       \
    S[6] = *(const f32x4*)(q2_ + 32);  S[7] = *(const f32x4*)(q2_ + 36);      \
  } while (0)

#define FWRITEB(S, WB, OPOFF)                                                 \
  do {                                                                        \
    char* d0_ = (WB) + (OPOFF) + wfrag;                                       \
    *(short8*)d0_ = pack8(S[0], S[1]);                                        \
    *(short8*)(d0_ + 1024) = pack8(S[2], S[3]);                               \
    char* d1_ = d0_ + 16384;                                                  \
    *(short8*)d1_ = pack8(S[4], S[5]);                                        \
    *(short8*)(d1_ + 1024) = pack8(S[6], S[7]);                               \
  } while (0)

#define FKK(RB, KKV)                                                          \
  do {                                                                        \
    _Pragma("unroll") for (int mi = 0; mi < 8; ++mi)                          \
        av[mi] = *(const short8*)((RB) +                                      \
            (((wm * 8 + mi) * 2 + (KKV)) << 10) + rdo);                       \
    _Pragma("unroll") for (int pp = 0; pp < 4; ++pp)                          \
        bv[pp] = *(const short8*)((RB) + 32768 +                              \
            (((wn * 4 + pp) * 2 + (KKV)) << 10) + rdo);                       \
    __builtin_amdgcn_s_setprio(1);                                            \
    _Pragma("unroll") for (int mi = 0; mi < 8; ++mi)                          \
        _Pragma("unroll") for (int pp = 0; pp < 4; ++pp)                      \
            acc[mi][pp] = __builtin_amdgcn_mfma_f32_16x16x32_bf16(            \
                av[mi], bv[pp], acc[mi][pp], 0, 0, 0);                        \
    __builtin_amdgcn_s_setprio(0);                                            \
  } while (0)

#define FPRO_WRITE(TT, ROFF)                                                  \
  do {                                                                        \
    short8 a_ = pack8(TT[0], TT[1]);                                          \
    short8 b_ = pack8(TT[2], TT[3]);                                          \
    char* d_ = smem + (ROFF) + wfrag;                                         \
    *(short8*)d_ = a_;                                                        \
    *(short8*)(d_ + 1024) = b_;                                               \
  } while (0)

__global__ __launch_bounds__(512, 2)
void ens_mlp_fallback(const float* __restrict__ X,
                      const float* __restrict__ W1,
                      const float* __restrict__ B1,
                      const float* __restrict__ W2,
                      const float* __restrict__ B2,
                      float* __restrict__ out)
{
    extern __shared__ char smem[];
    const int t    = threadIdx.x;
    const int lane = t & 63;
    const int wv   = t >> 6;
    const int wm   = wv >> 2;
    const int wn   = wv & 3;

    const int bb  = blockIdx.x;
    const int xcd = bb & 7;
    const int j   = bb >> 3;
    const int km  = xcd * 64 + (j >> 3);
    const int sub = j & 7;
    const int mt  = sub >> 1;
    const int nt  = sub & 1;

    const float* __restrict__ W1k = W1 + (size_t)km * (512 * 512);

    const int lr = t >> 2;
    const int c  = t & 3;
    const float* As = X   + (size_t)(mt * 256 + lr) * 512 + c * 8;
    const float* Bs = W1k + (size_t)(nt * 256 + lr) * 512 + c * 8;
    const int wfrag = ((lr >> 4) << 11) + (swz4((c << 4) | (lr & 15)) << 4);
    const int rdo   = swz4(lane) << 4;

    {
        f32x4 t0[4], t1[4], t2[4], t3[4];
        const float* q;
        q = As;          t0[0]=*(const f32x4*)q; t0[1]=*(const f32x4*)(q+4); t0[2]=*(const f32x4*)(q+32); t0[3]=*(const f32x4*)(q+36);
        q = As + 65536;  t1[0]=*(const f32x4*)q; t1[1]=*(const f32x4*)(q+4); t1[2]=*(const f32x4*)(q+32); t1[3]=*(const f32x4*)(q+36);
        q = Bs;          t2[0]=*(const f32x4*)q; t2[1]=*(const f32x4*)(q+4); t2[2]=*(const f32x4*)(q+32); t2[3]=*(const f32x4*)(q+36);
        q = Bs + 65536;  t3[0]=*(const f32x4*)q; t3[1]=*(const f32x4*)(q+4); t3[2]=*(const f32x4*)(q+32); t3[3]=*(const f32x4*)(q+36);
        asm volatile("s_waitcnt vmcnt(12)" ::: "memory"); FPRO_WRITE(t0, 0);
        asm volatile("s_waitcnt vmcnt(8)"  ::: "memory"); FPRO_WRITE(t1, 16384);
        asm volatile("s_waitcnt vmcnt(4)"  ::: "memory"); FPRO_WRITE(t2, 32768);
        asm volatile("s_waitcnt vmcnt(0)"  ::: "memory"); FPRO_WRITE(t3, 49152);
        asm volatile("s_waitcnt lgkmcnt(0)" ::: "memory");
        __builtin_amdgcn_sched_barrier(0);
        __builtin_amdgcn_s_barrier();
    }

    f32x4 acc[8][4];
#pragma unroll
    for (int i = 0; i < 8; ++i)
#pragma unroll
        for (int p = 0; p < 4; ++p)
            acc[i][p] = (f32x4)0.0f;

    short8 av[8], bv[4];
    f32x4 sS[8];

#pragma unroll 1
    for (int kt = 0; kt < 7; ++kt) {
        const char* rb = smem + (kt & 1) * 65536;
        char* wb       = smem + ((kt + 1) & 1) * 65536;

        FISSUE(sS, Bs, kt + 1);
        FKK(rb, 0);
        asm volatile("s_waitcnt vmcnt(0)" ::: "memory");
        FWRITEB(sS, wb, 32768);
        FISSUE(sS, As, kt + 1);
        FKK(rb, 1);
        asm volatile("s_waitcnt vmcnt(0)" ::: "memory");
        FWRITEB(sS, wb, 0);
        asm volatile("s_waitcnt lgkmcnt(0)" ::: "memory");
        __builtin_amdgcn_sched_barrier(0);
        __builtin_amdgcn_s_barrier();
    }
    {
        const char* rb = smem + 65536;
        FKK(rb, 0);
        FKK(rb, 1);
    }

    const int nc = lane & 15;
    const int kq = lane >> 4;
    float b1v[4], w2v[4];
#pragma unroll
    for (int pp = 0; pp < 4; ++pp) {
        int n = nt * 256 + (wn * 4 + pp) * 16 + nc;
        b1v[pp] = B1[km * 512 + n];
        w2v[pp] = W2[km * 512 + n];
    }

    float* lout = (float*)smem;
#pragma unroll
    for (int i = 0; i < 8; ++i) {
#pragma unroll
        for (int r = 0; r < 4; ++r) {
            float s = 0.f;
#pragma unroll
            for (int pp = 0; pp < 4; ++pp) {
                float h = acc[i][pp][r] + b1v[pp];
                h = h > 0.f ? h : 0.f;
                s += h * w2v[pp];
            }
#pragma unroll
            for (int d = 1; d < 16; d <<= 1)
                s += __shfl_xor(s, d, 64);
            if (nc == 0) {
                int row = wm * 128 + i * 16 + kq * 4 + r;
                lout[row * 4 + wn] = s;
            }
        }
    }
    __syncthreads();
    if (t < 256) {
        float s = lout[t * 4 + 0] + lout[t * 4 + 1] + lout[t * 4 + 2] + lout[t * 4 + 3];
        if (nt == 0) s += B2[km];
        int b = mt * 256 + t;
        atomicAdd(out + (size_t)b * 512 + (km & 7) * 64 + (km >> 3), s);
    }
}

extern "C" void kernel_launch(void* const* d_in, const int* in_sizes, int n_in,
                              void* d_out, int out_size, void* d_ws, size_t ws_size,
                              hipStream_t stream) {
    const float* X  = (const float*)d_in[0];
    const float* W1 = (const float*)d_in[1];
    const float* B1 = (const float*)d_in[2];
    const float* W2 = (const float*)d_in[3];
    const float* B2 = (const float*)d_in[4];
    float* out = (float*)d_out;

    hipMemsetAsync(out, 0, (size_t)out_size * sizeof(float), stream);

    const size_t NEED = 269484032ull;  // W1b 268MB + Xb 1MB (bf16, granule order)
    if (ws_size >= NEED) {
        short* WS = (short*)d_ws;
        ens_cvt<<<dim3(4112), dim3(256), 0, stream>>>(X, W1, WS);
        ens_gemm_dma<<<dim3(4096), dim3(512), 65536, stream>>>(
            WS + 134217728ull, WS, B1, W2, B2, out);
    } else {
        ens_mlp_fallback<<<dim3(4096), dim3(512), 131072, stream>>>(
            X, W1, B1, W2, B2, out);
    }
}